// Round 3
// baseline (246.686 us; speedup 1.0000x reference)
//
#include <hip/hip_runtime.h>
#include <math.h>

namespace {
constexpr int B_ = 32, I_ = 2048, J_ = 64, D_ = 8, E_ = 16;
constexpr int THREADS = 256;                 // 4 waves
constexpr int BPW = 4;                       // batches per wave (reg accum)
constexpr int BBLK = 16;                     // batches per block (4 waves * 4)
constexpr int PART_STRIDE = BBLK * J_ * E_;  // 16384 floats per block slot
constexpr int VSZ = B_ * J_ * E_;            // 32768
constexpr int WTILE = J_ * D_ * E_;          // 8192 floats = 32 KB per W[i]
constexpr int WQ = WTILE / 4;                // 2048 quads
}

// async global->LDS, 16B/lane. LDS dest linear (wave base + lane*16); the
// XOR-swizzle lives in the pre-permuted global source address (both-sides
// rule): LDS[q] = Wtile[q ^ ((q>>5)&7)], and reads apply the same XOR.
__device__ __forceinline__ void gload_lds16(const float* g, float* l) {
  __builtin_amdgcn_global_load_lds(
      (const __attribute__((address_space(1))) void*)g,
      (__attribute__((address_space(3))) void*)l, 16, 0, 0);
}

// One routing pass. Wave owns 4 batches; lane = j. W[i] double-buffered in
// LDS, consumed by all 16 block-batches (4 FMA-uses per W float per read).
// MODE 0: uniform c=1/64. MODE 1: logits = dot(uhat, v).
template <int MODE, int NIT>
__global__ __launch_bounds__(THREADS, 2) void caps_pass(
    const float* __restrict__ x, const float* __restrict__ W,
    const float* __restrict__ v, float* __restrict__ partial) {
  __shared__ float Wlds[2][WQ * 4];  // 2 x 32 KiB
  const int tid = threadIdx.x;
  const int wv = tid >> 6;
  const int j = tid & 63;
  const int ic = (int)blockIdx.x >> 1;
  const int bh = (int)blockIdx.x & 1;
  const int i0 = ic * NIT;
  const int b0 = bh * BBLK + BPW * wv;  // this wave's 4 global batches
  const int sw = j & 7;

  float vv[BPW][E_];
  if (MODE == 1) {
#pragma unroll
    for (int bb = 0; bb < BPW; ++bb) {
      const float4* vp = reinterpret_cast<const float4*>(
          v + ((size_t)(b0 + bb) * J_ + j) * E_);
#pragma unroll
      for (int q = 0; q < 4; ++q) {
        const float4 t = vp[q];
        vv[bb][4 * q + 0] = t.x; vv[bb][4 * q + 1] = t.y;
        vv[bb][4 * q + 2] = t.z; vv[bb][4 * q + 3] = t.w;
      }
    }
  }

  float acc[BPW][E_];
#pragma unroll
  for (int bb = 0; bb < BPW; ++bb)
#pragma unroll
    for (int e = 0; e < E_; ++e) acc[bb][e] = 0.0f;

  // prologue: stage W[i0] (2048 quads = 4 waves x 8 instr x 64 lanes)
  {
    const float* Wt = W + (size_t)i0 * WTILE;
#pragma unroll
    for (int it = 0; it < 8; ++it) {
      const int p = (wv * 8 + it) * 64 + j;
      const int src = p ^ ((p >> 5) & 7);
      gload_lds16(Wt + (size_t)src * 4, &Wlds[0][p * 4]);
    }
  }
  __syncthreads();

#pragma unroll 1
  for (int t = 0; t < NIT; ++t) {
    const int cur = t & 1;
    if (t + 1 < NIT) {
      const float* Wt = W + (size_t)(i0 + t + 1) * WTILE;
#pragma unroll
      for (int it = 0; it < 8; ++it) {
        const int p = (wv * 8 + it) * 64 + j;
        const int src = p ^ ((p >> 5) & 7);
        gload_lds16(Wt + (size_t)src * 4, &Wlds[cur ^ 1][p * 4]);
      }
    }
    const int i = i0 + t;
    float xs[BPW][D_];
#pragma unroll
    for (int bb = 0; bb < BPW; ++bb) {
      const float4* xp = reinterpret_cast<const float4*>(
          x + ((size_t)(b0 + bb) * I_ + i) * D_);
      const float4 t0 = xp[0], t1 = xp[1];
      xs[bb][0] = t0.x; xs[bb][1] = t0.y; xs[bb][2] = t0.z; xs[bb][3] = t0.w;
      xs[bb][4] = t1.x; xs[bb][5] = t1.y; xs[bb][6] = t1.z; xs[bb][7] = t1.w;
    }

    float uh[BPW][E_];
#pragma unroll
    for (int bb = 0; bb < BPW; ++bb)
#pragma unroll
      for (int e = 0; e < E_; ++e) uh[bb][e] = 0.0f;

    const float* buf = Wlds[cur];
    const int rowbase = j * 32;
#pragma unroll
    for (int k = 0; k < 32; ++k) {
      const float4 quad = *reinterpret_cast<const float4*>(
          buf + (size_t)(rowbase + (k ^ sw)) * 4);
      const int d = k >> 2;
      const int e0 = (k & 3) * 4;
#pragma unroll
      for (int bb = 0; bb < BPW; ++bb) {
        uh[bb][e0 + 0] = fmaf(xs[bb][d], quad.x, uh[bb][e0 + 0]);
        uh[bb][e0 + 1] = fmaf(xs[bb][d], quad.y, uh[bb][e0 + 1]);
        uh[bb][e0 + 2] = fmaf(xs[bb][d], quad.z, uh[bb][e0 + 2]);
        uh[bb][e0 + 3] = fmaf(xs[bb][d], quad.w, uh[bb][e0 + 3]);
      }
    }

    float c[BPW];
    if (MODE == 0) {
#pragma unroll
      for (int bb = 0; bb < BPW; ++bb) c[bb] = 1.0f / 64.0f;
    } else {
#pragma unroll
      for (int bb = 0; bb < BPW; ++bb) {
        float l0 = 0.f, l1 = 0.f, l2 = 0.f, l3 = 0.f;
#pragma unroll
        for (int e = 0; e < E_; e += 4) {
          l0 = fmaf(uh[bb][e + 0], vv[bb][e + 0], l0);
          l1 = fmaf(uh[bb][e + 1], vv[bb][e + 1], l1);
          l2 = fmaf(uh[bb][e + 2], vv[bb][e + 2], l2);
          l3 = fmaf(uh[bb][e + 3], vv[bb][e + 3], l3);
        }
        const float lg = (l0 + l1) + (l2 + l3);
        // |lg| <= ~25 -> expf safe without max-subtraction in fp32
        const float p = __expf(lg);
        float s = p;
#pragma unroll
        for (int off = 1; off < 64; off <<= 1) s += __shfl_xor(s, off);
        c[bb] = p / s;
      }
    }
#pragma unroll
    for (int bb = 0; bb < BPW; ++bb)
#pragma unroll
      for (int e = 0; e < E_; ++e)
        acc[bb][e] = fmaf(c[bb], uh[bb][e], acc[bb][e]);
    __syncthreads();
  }

  // partial[block][blocal][j][e], blocal = 4*wv + bb
  float* outp = partial + (size_t)blockIdx.x * PART_STRIDE +
                ((size_t)(BPW * wv) * J_ + j) * E_;
#pragma unroll
  for (int bb = 0; bb < BPW; ++bb) {
#pragma unroll
    for (int q = 0; q < 4; ++q) {
      float4 t;
      t.x = acc[bb][4 * q + 0]; t.y = acc[bb][4 * q + 1];
      t.z = acc[bb][4 * q + 2]; t.w = acc[bb][4 * q + 3];
      *reinterpret_cast<float4*>(outp + (size_t)bb * (J_ * E_) + q * 4) = t;
    }
  }
}

// Sum nic i-chunk partials for one (b, j-octet), squash, emit v.
// mode 0: v1 = squash(s); vsum = v1
// mode 1: vsum += squash(s)
// mode 2: out = squash(s)
__global__ __launch_bounds__(128) void caps_reduce(
    const float* __restrict__ partial, float* __restrict__ v1,
    float* __restrict__ vsum, float* __restrict__ out, const int mode,
    const int nic) {
  const int b = blockIdx.x >> 3;
  const int jg = blockIdx.x & 7;
  const int t = threadIdx.x;
  const int e = t & (E_ - 1);
  const int j = jg * 8 + (t >> 4);
  const int bh = b >> 4;
  const int bb = b & (BBLK - 1);
  const float* p =
      partial + (size_t)bh * PART_STRIDE + (size_t)bb * (J_ * E_) + j * E_ + e;
  float s = 0.0f;
#pragma unroll 8
  for (int icb = 0; icb < nic; ++icb)
    s += p[(size_t)icb * (2 * PART_STRIDE)];
  float sq = s * s;
  sq += __shfl_xor(sq, 1);
  sq += __shfl_xor(sq, 2);
  sq += __shfl_xor(sq, 4);
  sq += __shfl_xor(sq, 8);
  const float scale = sq / ((1.0f + sq) * sqrtf(sq));
  const float vv = s * scale;
  const int idx = (b * J_ + j) * E_ + e;
  if (mode == 0) {
    v1[idx] = vv;
    vsum[idx] = vv;
  } else if (mode == 1) {
    vsum[idx] += vv;
  } else {
    out[idx] = vv;
  }
}

extern "C" void kernel_launch(void* const* d_in, const int* in_sizes, int n_in,
                              void* d_out, int out_size, void* d_ws,
                              size_t ws_size, hipStream_t stream) {
  const float* x = (const float*)d_in[0];
  const float* W = (const float*)d_in[1];
  float* out = (float*)d_out;
  float* partial = (float*)d_ws;

  // NI=8 -> grid 512 (2 blocks/CU), partial = 32 MiB. Fall back to NI=16
  // (grid 256, 16 MiB) if scratch is small.
  const size_t need8 = ((size_t)512 * PART_STRIDE + 2 * VSZ) * sizeof(float);
  const bool big = ws_size >= need8;
  const int nblk = big ? 512 : 256;
  const int nic = big ? 256 : 128;
  float* v1 = partial + (size_t)nblk * PART_STRIDE;
  float* vsum = v1 + VSZ;

  if (big) {
    caps_pass<0, 8><<<nblk, THREADS, 0, stream>>>(x, W, nullptr, partial);
    caps_reduce<<<B_ * 8, 128, 0, stream>>>(partial, v1, vsum, out, 0, nic);
    caps_pass<1, 8><<<nblk, THREADS, 0, stream>>>(x, W, v1, partial);
    caps_reduce<<<B_ * 8, 128, 0, stream>>>(partial, v1, vsum, out, 1, nic);
    caps_pass<1, 8><<<nblk, THREADS, 0, stream>>>(x, W, vsum, partial);
    caps_reduce<<<B_ * 8, 128, 0, stream>>>(partial, v1, vsum, out, 2, nic);
  } else {
    caps_pass<0, 16><<<nblk, THREADS, 0, stream>>>(x, W, nullptr, partial);
    caps_reduce<<<B_ * 8, 128, 0, stream>>>(partial, v1, vsum, out, 0, nic);
    caps_pass<1, 16><<<nblk, THREADS, 0, stream>>>(x, W, v1, partial);
    caps_reduce<<<B_ * 8, 128, 0, stream>>>(partial, v1, vsum, out, 1, nic);
    caps_pass<1, 16><<<nblk, THREADS, 0, stream>>>(x, W, vsum, partial);
    caps_reduce<<<B_ * 8, 128, 0, stream>>>(partial, v1, vsum, out, 2, nic);
  }
}